// Round 1
// 761.129 us; speedup vs baseline: 1.0190x; 1.0190x over previous
//
#include <hip/hip_runtime.h>
#include <hip/hip_bf16.h>

// ---------------------------------------------------------------------------
// Net_15762529976343 — R3: GEMM redesign for A-streaming bandwidth.
//   - A (fp32 weights) loaded DIRECT to registers (no LDS round trip),
//     converted to bf16 via v_perm truncation in-reg.
//   - BN=256 (full N) per block, BM=128: A fetched exactly once from HBM.
//   - B double-buffered in LDS via global_load_lds with XOR-swizzled SOURCE
//     addresses -> bank-conflict-free ds_read_b128 on linear LDS writes.
//   - Pipeline: issue B(t+1)+A(t+1), s_waitcnt vmcnt(8) (never 0), raw
//     s_barrier. Prefetch stays in flight across barriers.
// ---------------------------------------------------------------------------

#define GK 18432
#define GN 200
#define NPAD 256

typedef __attribute__((ext_vector_type(8))) short bf16x8;
typedef __attribute__((ext_vector_type(4))) float f32x4;
typedef unsigned int u32;

// ---------------- im2col: in [8,2048,H,H] fp32 -> Bt [NPAD][GK] bf16 -------
__global__ __launch_bounds__(256) void im2col_bf16(
    const float* __restrict__ in, __hip_bfloat16* __restrict__ Bt,
    int H, int stride, int pad)
{
    int tid = blockIdx.x * 256 + threadIdx.x;   // NPAD*GK exactly
    int n = tid / GK;
    int k = tid - n * GK;
    float v = 0.f;
    if (n < GN) {
        int c = k / 9; int r9 = k - c * 9;
        int kh = r9 / 3, kw = r9 - kh * 3;
        int b = n / 25; int pp = n - b * 25;
        int oh = pp / 5, ow = pp - oh * 5;
        int r = oh * stride + kh - pad;
        int s = ow * stride + kw - pad;
        if (r >= 0 && r < H && s >= 0 && s < H)
            v = in[(((b * 2048 + c) * H) + r) * H + s];
    }
    Bt[tid] = __float2bfloat16(v);
}

// ---------------- grid_sample of padded f -> Bt [NPAD][GK] bf16 ------------
__global__ __launch_bounds__(256) void gridsample_bf16(
    const float* __restrict__ f, const float* __restrict__ gridb,
    __hip_bfloat16* __restrict__ Bt)
{
    int tid = blockIdx.x * 256 + threadIdx.x;
    int n = tid / GK;
    int cq = tid - n * GK;
    float v = 0.f;
    if (n < GN) {
        int c = cq / 9, q = cq - c * 9;
        int b = n / 25, p = n - b * 25;
        int g = (b * 225 + p * 9 + q) * 2;
        float px = gridb[g], py = gridb[g + 1];
        float x0f = floorf(px), y0f = floorf(py);
        int x0 = (int)x0f, y0 = (int)y0f;
        float wx1 = px - x0f, wx0 = 1.f - wx1;
        float wy1 = py - y0f, wy0 = 1.f - wy1;
        const float* fb = f + ((size_t)b * 2048 + c) * 25;
        // padded 7x7: nonzero only for 1<=x<=5, 1<=y<=5
        auto fetch = [&](int xi, int yi) -> float {
            if (xi < 1 || xi > 5 || yi < 1 || yi > 5) return 0.f;
            return fb[(yi - 1) * 5 + (xi - 1)];
        };
        v = fetch(x0, y0) * wx0 * wy0
          + fetch(x0 + 1, y0) * wx1 * wy0
          + fetch(x0, y0 + 1) * wx0 * wy1
          + fetch(x0 + 1, y0 + 1) * wx1 * wy1;
    }
    Bt[tid] = __float2bfloat16(v);
}

// ---------------- MFMA GEMM: C[M,200] += A_f32[M,GK] * Bt_bf16[n][k]^T -----
// BM=128, BN=256 (full N). 4 waves x (32 rows, 256 cols). z = K-split.
// Wave w: rows wm=w*32 (2 row-frags), 13 col-frags (cols 208..255 are pad).
__global__ __launch_bounds__(256, 2) void gemm_mfma(
    const float* __restrict__ A, const __hip_bfloat16* __restrict__ Bt,
    float* __restrict__ C, int M, int kchunk)
{
    __shared__ unsigned short Bs[2][256 * 32];   // 2 x 16 KB double buffer

    const int tid  = threadIdx.x;
    const int wave = tid >> 6, lane = tid & 63;
    const int lm = lane & 15, lq = lane >> 4;
    const int bm = blockIdx.y * 128;
    const int kbase = blockIdx.z * kchunk;
    const int wm = wave * 32;

    // ---- B staging: thread-constant pre-swizzled source offset.
    // phys 16B-slot (tid&3) of row (tid>>2)+64r holds logical k-chunk
    // (tid&3)^((tid>>3)&3)  (involution; reader applies same XOR).
    const int koff = (((tid & 3) ^ ((tid >> 3) & 3)) << 3);     // elements
    const __hip_bfloat16* bsrc = Bt + (size_t)(tid >> 2) * GK + kbase + koff;
    const int xk = lq ^ ((lm >> 1) & 3);                        // reader swizzle

    // ---- A row pointers (direct-to-register fragments) ----
    int r0 = bm + wm + lm;      if (r0 > M - 1) r0 = M - 1;
    int r1 = bm + wm + 16 + lm; if (r1 > M - 1) r1 = M - 1;
    const float* ap0 = A + (size_t)r0 * GK + kbase + lq * 8;
    const float* ap1 = A + (size_t)r1 * GK + kbase + lq * 8;

    f32x4 acc[2][13] = {};
    const int NS = kchunk >> 5;

    auto stageB = [&](int buf, int k0) {
        unsigned short* dst = &Bs[buf][tid * 8];
        const __hip_bfloat16* s = bsrc + k0;
#pragma unroll
        for (int r = 0; r < 4; ++r)
            __builtin_amdgcn_global_load_lds((const u32*)(s + (size_t)r * 64 * GK),
                                             (u32*)(dst + r * 2048), 16, 0, 0);
    };

    // prologue: B(0) + A(0) in flight
    stageB(0, 0);
    float4 ar00 = *(const float4*)(ap0 + 0);
    float4 ar01 = *(const float4*)(ap0 + 4);
    float4 ar10 = *(const float4*)(ap1 + 0);
    float4 ar11 = *(const float4*)(ap1 + 4);

    int cur = 0;
    for (int t = 0; t < NS; ++t) {
        // issue next-step loads (clamped on last iter to keep vmcnt pattern
        // uniform and addresses in bounds; data unused then)
        const int kn = (t + 1 < NS) ? ((t + 1) << 5) : (t << 5);
        stageB(cur ^ 1, kn);
        float4 an00 = *(const float4*)(ap0 + kn);
        float4 an01 = *(const float4*)(ap0 + kn + 4);
        float4 an10 = *(const float4*)(ap1 + kn);
        float4 an11 = *(const float4*)(ap1 + kn + 4);

        // convert A(t) -> bf16 frags (compiler inserts its own vmcnt for ar*)
        union { bf16x8 v; u32 u[4]; } af0, af1;
        af0.u[0] = __builtin_amdgcn_perm(__float_as_uint(ar00.y), __float_as_uint(ar00.x), 0x07060302u);
        af0.u[1] = __builtin_amdgcn_perm(__float_as_uint(ar00.w), __float_as_uint(ar00.z), 0x07060302u);
        af0.u[2] = __builtin_amdgcn_perm(__float_as_uint(ar01.y), __float_as_uint(ar01.x), 0x07060302u);
        af0.u[3] = __builtin_amdgcn_perm(__float_as_uint(ar01.w), __float_as_uint(ar01.z), 0x07060302u);
        af1.u[0] = __builtin_amdgcn_perm(__float_as_uint(ar10.y), __float_as_uint(ar10.x), 0x07060302u);
        af1.u[1] = __builtin_amdgcn_perm(__float_as_uint(ar10.w), __float_as_uint(ar10.z), 0x07060302u);
        af1.u[2] = __builtin_amdgcn_perm(__float_as_uint(ar11.y), __float_as_uint(ar11.x), 0x07060302u);
        af1.u[3] = __builtin_amdgcn_perm(__float_as_uint(ar11.w), __float_as_uint(ar11.z), 0x07060302u);

        // drain B(t)+A(t) only; B(t+1)+A(t+1) stay in flight across barrier
        asm volatile("s_waitcnt vmcnt(8)" ::: "memory");
        __builtin_amdgcn_s_barrier();

#pragma unroll
        for (int j = 0; j < 13; ++j) {
            bf16x8 b = *(const bf16x8*)&Bs[cur][(j * 16 + lm) * 32 + xk * 8];
            acc[0][j] = __builtin_amdgcn_mfma_f32_16x16x32_bf16(af0.v, b, acc[0][j], 0, 0, 0);
            acc[1][j] = __builtin_amdgcn_mfma_f32_16x16x32_bf16(af1.v, b, acc[1][j], 0, 0, 0);
        }

        asm volatile("" ::: "memory");     // keep ds_reads above this barrier
        __builtin_amdgcn_s_barrier();      // buf[cur] free for overwrite

        ar00 = an00; ar01 = an01; ar10 = an10; ar11 = an11;
        cur ^= 1;
    }

    // epilogue: acc[i][j][r] -> row = bm+wm+i*16+lq*4+r, col = j*16+lm
#pragma unroll
    for (int i = 0; i < 2; ++i) {
        int row0 = bm + wm + i * 16 + lq * 4;
#pragma unroll
        for (int j = 0; j < 13; ++j) {
            int col = j * 16 + lm;
            if (col < GN) {
#pragma unroll
                for (int r = 0; r < 4; ++r) {
                    int row = row0 + r;
                    if (row < M)
                        atomicAdd(&C[(size_t)row * GN + col], acc[i][j][r]);
                }
            }
        }
    }
}

// -------- BN stats: per-channel mean/rstd over 200 values ------------------
__global__ void bnstats_kernel(const float* __restrict__ y,
                               float* __restrict__ meanb,
                               float* __restrict__ rstdb)
{
    int ch = blockIdx.x;
    int lane = threadIdx.x;   // 64
    const float* p = y + (size_t)ch * GN;
    float s = 0.f, sq = 0.f;
    for (int idx = lane; idx < GN; idx += 64) {
        float v = p[idx];
        s += v; sq += v * v;
    }
    for (int off = 32; off; off >>= 1) {
        s += __shfl_down(s, off);
        sq += __shfl_down(sq, off);
    }
    if (lane == 0) {
        float m = s * (1.f / 200.f);
        float var = sq * (1.f / 200.f) - m * m;
        meanb[ch] = m;
        rstdb[ch] = rsqrtf(var + 1e-5f);
    }
}

// -------- BN apply + optional relu; [co][n] -> NCHW ------------------------
__global__ __launch_bounds__(256) void bn_apply_kernel(
    const float* __restrict__ y, const float* __restrict__ meanb,
    const float* __restrict__ rstdb, const float* __restrict__ g,
    const float* __restrict__ bb, float* __restrict__ out, int relu)
{
    int tid = blockIdx.x * 256 + threadIdx.x;   // 409600
    if (tid >= 409600) return;
    int b = tid / (2048 * 25);
    int rem = tid % (2048 * 25);
    int c = rem / 25;
    int pp = rem % 25;
    float v = y[(size_t)c * GN + b * 25 + pp];
    v = (v - meanb[c]) * rstdb[c] * g[c] + bb[c];
    if (relu) v = fmaxf(v, 0.f);
    out[tid] = v;
}

// -------- fc2 (relu of hmat folded here) -----------------------------------
__global__ void fc2_kernel(const float* __restrict__ hmat,
                           const float* __restrict__ fc2w,
                           float* __restrict__ pbuf)
{
    int n = blockIdx.x;            // 0..199
    int oo = threadIdx.x >> 6;     // 0..3
    int lane = threadIdx.x & 63;
    float s = 0.f;
#pragma unroll
    for (int j = 0; j < 8; ++j) {
        int hh = lane + 64 * j;
        s += fmaxf(hmat[(size_t)hh * GN + n], 0.f) * fc2w[oo * 512 + hh];
    }
    for (int off = 32; off; off >>= 1) s += __shfl_down(s, off);
    if (lane == 0) pbuf[n * 4 + oo] = s;
}

// -------- theta (d_out) + sampling grid pixel coords -----------------------
__global__ void theta_grids_kernel(const float* __restrict__ pbuf,
                                   float* __restrict__ gridb,
                                   float* __restrict__ outT)
{
    int tid = blockIdx.x * 256 + threadIdx.x;   // 1800
    if (tid >= 1800) return;
    int b = tid / 225;
    int rem = tid % 225;
    int p = rem / 9;
    int k = rem % 9;
    int i = p / 5, j = p % 5;
    int dy = k / 3, dx = k % 3;
    int n = b * 25 + p;
    float p0 = pbuf[n * 4 + 0];
    float p1 = pbuf[n * 4 + 1];
    float p2 = pbuf[n * 4 + 2];
    float p3 = pbuf[n * 4 + 3];
    float x = (float)(j + dx) * (1.f / 3.f) - 1.f;
    float y = (float)(i + dy) * (1.f / 3.f) - 1.f;
    float gx = (1.f + p0) * x + p1;
    float gy = (1.f + p2) * y + p3;
    gridb[tid * 2 + 0] = (gx + 1.f) * 3.f;
    gridb[tid * 2 + 1] = (gy + 1.f) * 3.f;
    if (k == 0) {
        outT[n * 6 + 0] = 1.f + p0;
        outT[n * 6 + 1] = 0.f;
        outT[n * 6 + 2] = p1;
        outT[n * 6 + 3] = 0.f;
        outT[n * 6 + 4] = 1.f + p2;
        outT[n * 6 + 5] = p3;
    }
}

// -------- softmax over 201*25 per batch (+bias) ----------------------------
__global__ void softmax_kernel(const float* __restrict__ stn,
                               const float* __restrict__ bias,
                               float* __restrict__ outC,
                               float* __restrict__ outS)
{
    int b = blockIdx.x;
    __shared__ float red[256];
    int t = threadIdx.x;

    float mx = -1e30f;
    for (int idx = t; idx < 5025; idx += 256) {
        int o = idx / 25, pp = idx % 25;
        mx = fmaxf(mx, stn[(size_t)o * GN + b * 25 + pp] + bias[o]);
    }
    red[t] = mx; __syncthreads();
    for (int s = 128; s; s >>= 1) {
        if (t < s) red[t] = fmaxf(red[t], red[t + s]);
        __syncthreads();
    }
    mx = red[0]; __syncthreads();

    float sm = 0.f;
    for (int idx = t; idx < 5025; idx += 256) {
        int o = idx / 25, pp = idx % 25;
        sm += expf(stn[(size_t)o * GN + b * 25 + pp] + bias[o] - mx);
    }
    red[t] = sm; __syncthreads();
    for (int s = 128; s; s >>= 1) {
        if (t < s) red[t] += red[t + s];
        __syncthreads();
    }
    float inv = 1.f / red[0];

    for (int idx = t; idx < 5025; idx += 256) {
        int o = idx / 25, pp = idx % 25;
        outS[b * 5025 + idx] =
            expf(stn[(size_t)o * GN + b * 25 + pp] + bias[o] - mx) * inv;
    }
    for (int o = t; o < 201; o += 256) {
        float cs = 0.f;
        for (int pp = 0; pp < 25; ++pp)
            cs += expf(stn[(size_t)o * GN + b * 25 + pp] + bias[o] - mx);
        outC[b * 201 + o] = cs * inv;
    }
}

// ---------------------------------------------------------------------------
extern "C" void kernel_launch(void* const* d_in, const int* in_sizes, int n_in,
                              void* d_out, int out_size, void* d_ws, size_t ws_size,
                              hipStream_t stream)
{
    const float* x           = (const float*)d_in[0];
    const float* conv_last_w = (const float*)d_in[3];
    const float* bn_last_g   = (const float*)d_in[4];
    const float* bn_last_b   = (const float*)d_in[5];
    const float* loc_w1      = (const float*)d_in[6];
    const float* loc_g1      = (const float*)d_in[7];
    const float* loc_b1      = (const float*)d_in[8];
    const float* loc_w2      = (const float*)d_in[9];
    const float* loc_g2      = (const float*)d_in[10];
    const float* loc_b2      = (const float*)d_in[11];
    const float* fc1_w       = (const float*)d_in[12];
    const float* fc2_w       = (const float*)d_in[13];
    const float* conv_stn_w  = (const float*)d_in[14];
    const float* conv_stn_b  = (const float*)d_in[15];

    __hip_bfloat16* Bt = (__hip_bfloat16*)d_ws;          // NPAD*GK bf16 = 9.44 MB
    float* fp    = (float*)((char*)d_ws + (size_t)NPAD * GK * 2);
    float* t1    = fp;                       // 409,600
    float* fbuf  = t1 + 409600;              // 409,600
    float* xs1   = fbuf + 409600;            // 409,600
    float* xs    = xs1 + 409600;             // 409,600
    float* hmat  = xs + 409600;              // 102,400
    float* stn   = hmat + 102400;            // 40,200
    float* pbuf  = stn + 40200;              // 800
    float* gridb = pbuf + 800;               // 3,600
    float* meanb = gridb + 3600;             // 2,048
    float* rstdb = meanb + 2048;             // 2,048

    float* outC = (float*)d_out;             // [8,201]
    float* outS = outC + 8 * 201;            // [8,201,5,5]
    float* outT = outS + 8 * 201 * 25;       // [200,2,3]

    dim3 b256(256);
    const int nB = (NPAD * GK) / 256;        // 18432 blocks

    // conv_last (s2,p1) + bn -> fbuf
    im2col_bf16<<<nB, b256, 0, stream>>>(x, Bt, 10, 2, 1);
    hipMemsetAsync(t1, 0, 409600 * sizeof(float), stream);
    gemm_mfma<<<dim3(1, 16, 16), b256, 0, stream>>>(conv_last_w, Bt, t1, 2048, GK / 16);
    bnstats_kernel<<<2048, 64, 0, stream>>>(t1, meanb, rstdb);
    bn_apply_kernel<<<1600, b256, 0, stream>>>(t1, meanb, rstdb, bn_last_g, bn_last_b, fbuf, 0);

    // loc conv1 + bn + relu -> xs1
    im2col_bf16<<<nB, b256, 0, stream>>>(fbuf, Bt, 5, 1, 1);
    hipMemsetAsync(t1, 0, 409600 * sizeof(float), stream);
    gemm_mfma<<<dim3(1, 16, 16), b256, 0, stream>>>(loc_w1, Bt, t1, 2048, GK / 16);
    bnstats_kernel<<<2048, 64, 0, stream>>>(t1, meanb, rstdb);
    bn_apply_kernel<<<1600, b256, 0, stream>>>(t1, meanb, rstdb, loc_g1, loc_b1, xs1, 1);

    // loc conv2 + bn + relu -> xs
    im2col_bf16<<<nB, b256, 0, stream>>>(xs1, Bt, 5, 1, 1);
    hipMemsetAsync(t1, 0, 409600 * sizeof(float), stream);
    gemm_mfma<<<dim3(1, 16, 16), b256, 0, stream>>>(loc_w2, Bt, t1, 2048, GK / 16);
    bnstats_kernel<<<2048, 64, 0, stream>>>(t1, meanb, rstdb);
    bn_apply_kernel<<<1600, b256, 0, stream>>>(t1, meanb, rstdb, loc_g2, loc_b2, xs, 1);

    // fc1 (patches == im2col(xs)); relu folded into fc2 read
    im2col_bf16<<<nB, b256, 0, stream>>>(xs, Bt, 5, 1, 1);
    hipMemsetAsync(hmat, 0, 102400 * sizeof(float), stream);
    gemm_mfma<<<dim3(1, 4, 64), b256, 0, stream>>>(fc1_w, Bt, hmat, 512, GK / 64);

    // fc2 -> p; theta -> d_out; grids
    fc2_kernel<<<200, 256, 0, stream>>>(hmat, fc2_w, pbuf);
    theta_grids_kernel<<<8, 256, 0, stream>>>(pbuf, gridb, outT);

    // grid_sample -> Bt (im2col layout of temp)
    gridsample_bf16<<<nB, b256, 0, stream>>>(fbuf, gridb, Bt);

    // conv_stn (bias folded into softmax)
    hipMemsetAsync(stn, 0, 40200 * sizeof(float), stream);
    gemm_mfma<<<dim3(1, 2, 64), b256, 0, stream>>>(conv_stn_w, Bt, stn, 201, GK / 64);

    // softmax + outputs
    softmax_kernel<<<8, 256, 0, stream>>>(stn, conv_stn_b, outC, outS);
}